// Round 5
// baseline (84.759 us; speedup 1.0000x reference)
//
#include <hip/hip_runtime.h>
#include <stdint.h>

#define B_  32
#define C_  256
#define HW_ 4096
#define K_  1024

typedef float floatx4 __attribute__((ext_vector_type(4)));

__device__ __forceinline__ uint32_t f2key(float f) {
    uint32_t b = __float_as_uint(f);
    return b ^ ((b & 0x80000000u) ? 0xFFFFFFFFu : 0x80000000u);
}

// Kernel A: per-pixel channel sums, float4 over pixels, channel-split x4 for occupancy.
// 512 blocks x 256 threads. Lane group of 4 owns one float4-pixel: phase j sums
// channels c == j (mod 4) sequentially, then shfl-combine as (s0+s1)+(s2+s3) --
// bit-identical to the proven round-1/2 summation order (absmax must stay 0).
__global__ void __launch_bounds__(256) ps_sum_kernel(const float4* __restrict__ f4,
                                                     float4* __restrict__ sums4) {
    int gid   = blockIdx.x * 256 + threadIdx.x;    // 0..131071
    int pix4  = gid >> 2;                          // global float4-pixel id 0..32767
    int phase = gid & 3;
    int b     = pix4 >> 10;                        // 1024 float4-pixels per batch
    int p4    = pix4 & 1023;
    const float4* base = f4 + (size_t)b * C_ * (HW_ / 4) + p4;

    float4 s = {0.f, 0.f, 0.f, 0.f};
    #pragma unroll 8
    for (int c = phase; c < C_; c += 4) {
        float4 v = base[(size_t)c * (HW_ / 4)];
        s.x += v.x; s.y += v.y; s.z += v.z; s.w += v.w;
    }
    // combine phases: r = (s0+s1)+(s2+s3), exact order per component
    float4 t1;
    t1.x = __shfl_xor(s.x, 1); t1.y = __shfl_xor(s.y, 1);
    t1.z = __shfl_xor(s.z, 1); t1.w = __shfl_xor(s.w, 1);
    float4 r1;
    r1.x = s.x + t1.x; r1.y = s.y + t1.y; r1.z = s.z + t1.z; r1.w = s.w + t1.w;
    float4 t2;
    t2.x = __shfl_xor(r1.x, 2); t2.y = __shfl_xor(r1.y, 2);
    t2.z = __shfl_xor(r1.z, 2); t2.w = __shfl_xor(r1.w, 2);
    float4 r;
    r.x = r1.x + t2.x; r.y = r1.y + t2.y; r.z = r1.z + t2.z; r.w = r1.w + t2.w;

    if (phase == 0)
        sums4[(size_t)b * (HW_ / 4) + p4] = r;
}

// Kernel B (fused select+apply): 512 blocks x 1024 threads.
// Block = (batch b, 16-channel slice c0). Prologue: per-block redundant exact
// radix select over the batch's 4096 sums (identical result in every block of
// the batch; deterministic). Thread t's mask float4 covers exactly the pixel
// column it applies -> mask stays in a register, reused across 16 channels.
__global__ void __launch_bounds__(1024) ps_select_apply_kernel(
        const float* __restrict__ sums,
        const float4* __restrict__ f4,
        float* __restrict__ out) {
    __shared__ uint32_t bins[256];
    __shared__ uint32_t wred[16];
    __shared__ uint32_t sh_bcast[2];

    const int b    = blockIdx.x >> 4;
    const int c0   = (blockIdx.x & 15) << 4;
    const int t    = threadIdx.x;
    const int lane = t & 63;
    const int wid  = t >> 6;

    float4 v = ((const float4*)(sums + (size_t)b * HW_))[t];
    uint32_t k0 = f2key(v.x), k1 = f2key(v.y), k2 = f2key(v.z), k3 = f2key(v.w);

    uint32_t prefix = 0;
    uint32_t krem   = K_;
    #pragma unroll
    for (int shift = 24; shift >= 0; shift -= 8) {
        if (t < 256) bins[t] = 0;
        __syncthreads();
        uint32_t abovemask = (shift == 24) ? 0u : (0xFFFFFFFFu << (shift + 8));
        if ((k0 & abovemask) == prefix) atomicAdd(&bins[(k0 >> shift) & 255], 1u);
        if ((k1 & abovemask) == prefix) atomicAdd(&bins[(k1 >> shift) & 255], 1u);
        if ((k2 & abovemask) == prefix) atomicAdd(&bins[(k2 >> shift) & 255], 1u);
        if ((k3 & abovemask) == prefix) atomicAdd(&bins[(k3 >> shift) & 255], 1u);
        __syncthreads();
        uint32_t s = 0, binv = 0;
        if (t < 256) {
            int jbin = 255 - t;                    // scan bins from the top
            binv = bins[jbin];
            s = binv;
            #pragma unroll
            for (int off = 1; off < 64; off <<= 1) {
                uint32_t u = __shfl_up(s, off);
                if (lane >= off) s += u;
            }
            if (lane == 63) wred[wid] = s;
        }
        __syncthreads();
        if (t < 256) {
            int jbin = 255 - t;
            uint32_t add = 0;
            for (int w = 0; w < wid; ++w) add += wred[w];
            uint32_t sfx_incl = s + add;           // suffix sum over bins >= jbin
            uint32_t sfx_excl = sfx_incl - binv;   // suffix sum over bins >  jbin
            if (sfx_incl >= krem && sfx_excl < krem) {
                sh_bcast[0] = prefix | ((uint32_t)jbin << shift);
                sh_bcast[1] = krem - sfx_excl;
            }
        }
        __syncthreads();
        prefix = sh_bcast[0];
        krem   = sh_bcast[1];
        __syncthreads();
    }

    const uint32_t T    = prefix;                  // k-th largest key
    const uint32_t need = krem;                    // ties to include, lowest index first

    uint32_t e0 = (k0 == T), e1 = (k1 == T), e2 = (k2 == T), e3 = (k3 == T);
    uint32_t c  = e0 + e1 + e2 + e3;

    // exclusive prefix over 1024 threads (thread order == pixel order)
    uint32_t sc = c;
    #pragma unroll
    for (int off = 1; off < 64; off <<= 1) {
        uint32_t u = __shfl_up(sc, off);
        if (lane >= off) sc += u;
    }
    if (lane == 63) wred[wid] = sc;
    __syncthreads();
    uint32_t add = 0;
    for (int w = 0; w < wid; ++w) add += wred[w];
    uint32_t run = (sc - c) + add;                 // ties at lower pixel index

    float4 m;
    m.x = ((k0 > T) || (e0 && run < need)) ? 0.0f : 1.0f; run += e0;
    m.y = ((k1 > T) || (e1 && run < need)) ? 0.0f : 1.0f; run += e1;
    m.z = ((k2 > T) || (e2 && run < need)) ? 0.0f : 1.0f; run += e2;
    m.w = ((k3 > T) || (e3 && run < need)) ? 0.0f : 1.0f; run += e3;

    // Apply: 16 channels, column t; mask float4 register-resident throughout.
    const float4* src = f4 + ((size_t)b * C_ + c0) * (HW_ / 4) + t;
    float*        dst = out + (((size_t)b * C_ + c0) * (HW_ / 4) + t) * 4;
    #pragma unroll
    for (int j = 0; j < 16; ++j) {
        float4 x = src[(size_t)j * (HW_ / 4)];
        floatx4 r;
        r.x = x.x * m.x; r.y = x.y * m.y; r.z = x.z * m.z; r.w = x.w * m.w;
        __builtin_nontemporal_store(r, (floatx4*)(dst + (size_t)j * HW_));
    }
}

extern "C" void kernel_launch(void* const* d_in, const int* in_sizes, int n_in,
                              void* d_out, int out_size, void* d_ws, size_t ws_size,
                              hipStream_t stream) {
    const float* f = (const float*)d_in[0];
    float* out = (float*)d_out;

    float* sums = (float*)d_ws;                        // 32*4096 floats = 512 KiB

    ps_sum_kernel<<<dim3(512), dim3(256), 0, stream>>>((const float4*)f, (float4*)sums);
    ps_select_apply_kernel<<<dim3(512), dim3(1024), 0, stream>>>(
        sums, (const float4*)f, out);
}

// Round 6
// 76.444 us; speedup vs baseline: 1.1088x; 1.1088x over previous
//
#include <hip/hip_runtime.h>
#include <stdint.h>

#define B_  32
#define C_  256
#define HW_ 4096
#define K_  1024

typedef float floatx4 __attribute__((ext_vector_type(4)));

__device__ __forceinline__ uint32_t f2key(float f) {
    uint32_t b = __float_as_uint(f);
    return b ^ ((b & 0x80000000u) ? 0xFFFFFFFFu : 0x80000000u);
}

// Kernel A: per-pixel channel sums, float4 over pixels (exact round-2 version,
// best measured). 512 blocks x 64 threads; each thread owns 4 consecutive pixels.
// Per-pixel arithmetic order: 4 interleaved chains, (s0+s1)+(s2+s3) -- bit-exact.
__global__ void ps_sum_kernel(const float4* __restrict__ f4, float4* __restrict__ sums4) {
    int gid = blockIdx.x * 64 + threadIdx.x;       // 0..32767
    int b   = gid >> 10;                           // 1024 float4-pixels per batch
    int p4  = gid & 1023;
    const float4* base = f4 + (size_t)b * C_ * (HW_ / 4) + p4;
    float4 s0 = {0,0,0,0}, s1 = {0,0,0,0}, s2 = {0,0,0,0}, s3 = {0,0,0,0};
    #pragma unroll 4
    for (int c = 0; c < C_; c += 4) {
        float4 v0 = base[(size_t)(c + 0) * (HW_ / 4)];
        float4 v1 = base[(size_t)(c + 1) * (HW_ / 4)];
        float4 v2 = base[(size_t)(c + 2) * (HW_ / 4)];
        float4 v3 = base[(size_t)(c + 3) * (HW_ / 4)];
        s0.x += v0.x; s0.y += v0.y; s0.z += v0.z; s0.w += v0.w;
        s1.x += v1.x; s1.y += v1.y; s1.z += v1.z; s1.w += v1.w;
        s2.x += v2.x; s2.y += v2.y; s2.z += v2.z; s2.w += v2.w;
        s3.x += v3.x; s3.y += v3.y; s3.z += v3.z; s3.w += v3.w;
    }
    float4 r;
    r.x = (s0.x + s1.x) + (s2.x + s3.x);
    r.y = (s0.y + s1.y) + (s2.y + s3.y);
    r.z = (s0.z + s1.z) + (s2.z + s3.z);
    r.w = (s0.w + s1.w) + (s2.w + s3.w);
    sums4[(size_t)b * (HW_ / 4) + p4] = r;
}

// Kernel B: per-batch exact top-K threshold (radix select) + tie-aware mask.
// 32 blocks x 1024 threads. Each thread owns 4 keys in registers throughout.
__global__ void __launch_bounds__(1024) ps_select_kernel(const float* __restrict__ sums,
                                                         float* __restrict__ mask) {
    __shared__ uint32_t bins[256];
    __shared__ uint32_t wred[16];
    __shared__ uint32_t sh_bcast[2];

    const int b    = blockIdx.x;
    const int t    = threadIdx.x;
    const int lane = t & 63;
    const int wid  = t >> 6;

    float4 v = ((const float4*)(sums + (size_t)b * HW_))[t];
    uint32_t k0 = f2key(v.x), k1 = f2key(v.y), k2 = f2key(v.z), k3 = f2key(v.w);

    uint32_t prefix = 0;
    uint32_t krem   = K_;
    #pragma unroll
    for (int shift = 24; shift >= 0; shift -= 8) {
        if (t < 256) bins[t] = 0;
        __syncthreads();
        uint32_t abovemask = (shift == 24) ? 0u : (0xFFFFFFFFu << (shift + 8));
        if ((k0 & abovemask) == prefix) atomicAdd(&bins[(k0 >> shift) & 255], 1u);
        if ((k1 & abovemask) == prefix) atomicAdd(&bins[(k1 >> shift) & 255], 1u);
        if ((k2 & abovemask) == prefix) atomicAdd(&bins[(k2 >> shift) & 255], 1u);
        if ((k3 & abovemask) == prefix) atomicAdd(&bins[(k3 >> shift) & 255], 1u);
        __syncthreads();
        uint32_t s = 0, binv = 0;
        if (t < 256) {
            int jbin = 255 - t;                    // scan bins from the top
            binv = bins[jbin];
            s = binv;
            #pragma unroll
            for (int off = 1; off < 64; off <<= 1) {
                uint32_t u = __shfl_up(s, off);
                if (lane >= off) s += u;
            }
            if (lane == 63) wred[wid] = s;
        }
        __syncthreads();
        if (t < 256) {
            int jbin = 255 - t;
            uint32_t add = 0;
            for (int w = 0; w < wid; ++w) add += wred[w];
            uint32_t sfx_incl = s + add;           // suffix sum over bins >= jbin
            uint32_t sfx_excl = sfx_incl - binv;   // suffix sum over bins >  jbin
            if (sfx_incl >= krem && sfx_excl < krem) {
                sh_bcast[0] = prefix | ((uint32_t)jbin << shift);
                sh_bcast[1] = krem - sfx_excl;
            }
        }
        __syncthreads();
        prefix = sh_bcast[0];
        krem   = sh_bcast[1];
        __syncthreads();
    }

    const uint32_t T    = prefix;                  // k-th largest key
    const uint32_t need = krem;                    // ties to include, lowest index first

    uint32_t e0 = (k0 == T), e1 = (k1 == T), e2 = (k2 == T), e3 = (k3 == T);
    uint32_t c  = e0 + e1 + e2 + e3;

    // exclusive prefix over 1024 threads (thread order == pixel order)
    uint32_t sc = c;
    #pragma unroll
    for (int off = 1; off < 64; off <<= 1) {
        uint32_t u = __shfl_up(sc, off);
        if (lane >= off) sc += u;
    }
    if (lane == 63) wred[wid] = sc;
    __syncthreads();
    uint32_t add = 0;
    for (int w = 0; w < wid; ++w) add += wred[w];
    uint32_t run = (sc - c) + add;                 // ties at lower pixel index

    float4 m;
    m.x = ((k0 > T) || (e0 && run < need)) ? 0.0f : 1.0f; run += e0;
    m.y = ((k1 > T) || (e1 && run < need)) ? 0.0f : 1.0f; run += e1;
    m.z = ((k2 > T) || (e2 && run < need)) ? 0.0f : 1.0f; run += e2;
    m.w = ((k3 > T) || (e3 && run < need)) ? 0.0f : 1.0f; run += e3;
    ((float4*)(mask + (size_t)b * HW_))[t] = m;
}

// Kernel C: out = f * mask (broadcast over channels), float4 loads + NT store.
// SINGLE CHANGE vs round-2: __builtin_nontemporal_store on the output, so the
// write does not allocate in L3 and f (just read by the sum pass, 128 MiB of
// 256 MiB L3) stays resident for apply's read.
__global__ void ps_apply_kernel(const float4* __restrict__ f4,
                                const float4* __restrict__ mask4,
                                float* __restrict__ out) {
    size_t i = (size_t)blockIdx.x * blockDim.x + threadIdx.x;  // over 8388608 float4s
    float4 v = f4[i];
    size_t b  = i >> 18;           // (C_*HW_/4) = 262144 float4 per batch
    size_t p4 = i & 1023;          // HW_/4 - 1
    float4 m = mask4[(b << 10) + p4];
    floatx4 r;
    r.x = v.x * m.x; r.y = v.y * m.y; r.z = v.z * m.z; r.w = v.w * m.w;
    __builtin_nontemporal_store(r, (floatx4*)(out + i * 4));
}

extern "C" void kernel_launch(void* const* d_in, const int* in_sizes, int n_in,
                              void* d_out, int out_size, void* d_ws, size_t ws_size,
                              hipStream_t stream) {
    const float* f = (const float*)d_in[0];
    float* out = (float*)d_out;

    float* sums = (float*)d_ws;                        // 32*4096 floats = 512 KiB
    float* mask = sums + (size_t)B_ * HW_;             // 32*4096 floats = 512 KiB

    ps_sum_kernel<<<dim3(512), dim3(64), 0, stream>>>((const float4*)f, (float4*)sums);
    ps_select_kernel<<<dim3(B_), dim3(1024), 0, stream>>>(sums, mask);

    size_t total4 = (size_t)B_ * C_ * HW_ / 4;         // 8388608
    ps_apply_kernel<<<dim3((unsigned)(total4 / 256)), dim3(256), 0, stream>>>(
        (const float4*)f, (const float4*)mask, out);
}